// Round 4
// baseline (1419.863 us; speedup 1.0000x reference)
//
#include <hip/hip_runtime.h>

typedef __attribute__((ext_vector_type(8))) short bf16x8;
typedef __attribute__((ext_vector_type(4))) float f32x4;
typedef unsigned short u16;

__device__ __forceinline__ u16 f2bf(float f) {
  union { float f; unsigned u; } v; v.f = f;
  unsigned r = v.u + 0x7fffu + ((v.u >> 16) & 1u);
  return (u16)(r >> 16);
}
__device__ __forceinline__ float bf2f(u16 s) {
  union { unsigned u; float f; } v; v.u = ((unsigned)s) << 16;
  return v.f;
}
__device__ __forceinline__ f32x4 mfma_bf16(bf16x8 a, bf16x8 b, f32x4 c) {
  return __builtin_amdgcn_mfma_f32_16x16x32_bf16(a, b, c, 0, 0, 0);
}
__device__ __forceinline__ void split2(float x, u16& h, u16& l) {
  h = f2bf(x);
  l = f2bf(x - bf2f(h));
}
template <int SPL>
__device__ __forceinline__ void splitN(float x, u16* o) {
  float r = x;
  #pragma unroll
  for (int i = 0; i < SPL; i++) {
    o[i] = f2bf(r);
    if (i + 1 < SPL) r = r - bf2f(o[i]);
  }
}

// ---------------- LayerNorm full output (fp32), one wave per row ----------------
__global__ __launch_bounds__(256) void ln_kernel(
    const float* __restrict__ x, const float* __restrict__ gamma,
    const float* __restrict__ beta, float* __restrict__ o, int rows, int C) {
  int wid = threadIdx.x >> 6, lane = threadIdx.x & 63;
  int row = blockIdx.x * 4 + wid;
  if (row >= rows) return;
  const float* xr = x + (size_t)row * C;
  float s = 0.f, s2 = 0.f;
  for (int c = lane; c < C; c += 64) { float v = xr[c]; s += v; s2 += v * v; }
  #pragma unroll
  for (int off = 32; off >= 1; off >>= 1) {
    s += __shfl_xor(s, off);
    s2 += __shfl_xor(s2, off);
  }
  float m = s / C;
  float var = s2 / C - m * m;
  float rs = rsqrtf(var + 1e-5f);
  float* orow = o + (size_t)row * C;
  for (int c = lane; c < C; c += 64) orow[c] = (xr[c] - m) * rs * gamma[c] + beta[c];
}

// ------- Dense GEMM, SPL-way bf16 split. 32(M)x64(N) tile, 128 threads. -------
// LNA=2: LayerNorm A from row-partials pin (K must be 384).
// STATS: emit per-block row partials {sum,sumsq} of final O values into pout.
// OUT2: also write final value to O2.
template <int SPL, int LNA, int INRELU, int ACT, int ACC, int STATS, int OUT2>
__global__ __launch_bounds__(128) void gemm_kernel(
    const float* __restrict__ A, const float* __restrict__ pin,
    const float* __restrict__ lng, const float* __restrict__ lnb,
    const float* __restrict__ W, const float* __restrict__ bias,
    float* __restrict__ O, float* __restrict__ O2, float* __restrict__ pout,
    int M, int N, int K) {
  __shared__ __align__(16) u16 a_pl[SPL][32][40];
  __shared__ __align__(16) u16 w_pl[SPL][64][40];
  const int n0 = blockIdx.x * 64, m0 = blockIdx.y * 32;
  const int t = threadIdx.x;
  const int wid = t >> 6, lane = t & 63;
  const int cl = lane & 15, cg = lane >> 4;
  const int ar = t >> 2, aq = t & 3;
  const int wr = t >> 1, wh = t & 1;
  const float* ap = A + (size_t)(m0 + ar) * K + aq * 8;
  const float* wp = W + (size_t)(n0 + wr) * K + wh * 16;
  float rm = 0.f, rrs = 1.f;
  if (LNA) {
    float s = 0.f, s2 = 0.f;
    #pragma unroll
    for (int pq = 0; pq < 6; pq++) {
      s  += pin[(m0 + ar) * 16 + pq * 2];
      s2 += pin[(m0 + ar) * 16 + pq * 2 + 1];
    }
    rm = s * (1.f / 384.f);
    float var = s2 * (1.f / 384.f) - rm * rm;
    rrs = rsqrtf(var + 1e-5f);
  }
  float4 ra0, ra1, rw0, rw1, rw2, rw3, rg0, rg1, rb0, rb1;
  #define GLOADD(k0) do { \
    ra0 = ((const float4*)(ap + (k0)))[0]; ra1 = ((const float4*)(ap + (k0)))[1]; \
    rw0 = ((const float4*)(wp + (k0)))[0]; rw1 = ((const float4*)(wp + (k0)))[1]; \
    rw2 = ((const float4*)(wp + (k0)))[2]; rw3 = ((const float4*)(wp + (k0)))[3]; \
    if (LNA) { \
      rg0 = ((const float4*)(lng + (k0) + aq * 8))[0]; rg1 = ((const float4*)(lng + (k0) + aq * 8))[1]; \
      rb0 = ((const float4*)(lnb + (k0) + aq * 8))[0]; rb1 = ((const float4*)(lnb + (k0) + aq * 8))[1]; \
    } } while (0)
  GLOADD(0);
  f32x4 acc[4] = {};
  for (int k0 = 0; k0 < K; k0 += 32) {
    {
      float av[8] = {ra0.x, ra0.y, ra0.z, ra0.w, ra1.x, ra1.y, ra1.z, ra1.w};
      if (LNA) {
        float gv[8] = {rg0.x, rg0.y, rg0.z, rg0.w, rg1.x, rg1.y, rg1.z, rg1.w};
        float bv[8] = {rb0.x, rb0.y, rb0.z, rb0.w, rb1.x, rb1.y, rb1.z, rb1.w};
        #pragma unroll
        for (int j = 0; j < 8; j++) av[j] = (av[j] - rm) * rrs * gv[j] + bv[j];
      }
      if (INRELU) {
        #pragma unroll
        for (int j = 0; j < 8; j++) av[j] = fmaxf(av[j], 0.f);
      }
      union { u16 s[8]; uint4 u; } pk[SPL];
      #pragma unroll
      for (int j = 0; j < 8; j++) {
        u16 tmp[SPL]; splitN<SPL>(av[j], tmp);
        #pragma unroll
        for (int p2 = 0; p2 < SPL; p2++) pk[p2].s[j] = tmp[p2];
      }
      #pragma unroll
      for (int p2 = 0; p2 < SPL; p2++) *(uint4*)&a_pl[p2][ar][aq * 8] = pk[p2].u;
      float wv[16] = {rw0.x, rw0.y, rw0.z, rw0.w, rw1.x, rw1.y, rw1.z, rw1.w,
                      rw2.x, rw2.y, rw2.z, rw2.w, rw3.x, rw3.y, rw3.z, rw3.w};
      #pragma unroll
      for (int hlf = 0; hlf < 2; hlf++) {
        #pragma unroll
        for (int j = 0; j < 8; j++) {
          u16 tmp[SPL]; splitN<SPL>(wv[hlf * 8 + j], tmp);
          #pragma unroll
          for (int p2 = 0; p2 < SPL; p2++) pk[p2].s[j] = tmp[p2];
        }
        #pragma unroll
        for (int p2 = 0; p2 < SPL; p2++) *(uint4*)&w_pl[p2][wr][wh * 16 + hlf * 8] = pk[p2].u;
      }
    }
    __syncthreads();
    if (k0 + 32 < K) GLOADD(k0 + 32);
    bf16x8 av[SPL];
    #pragma unroll
    for (int p2 = 0; p2 < SPL; p2++) av[p2] = *(const bf16x8*)&a_pl[p2][wid * 16 + cl][cg * 8];
    bf16x8 bv[SPL][4];
    #pragma unroll
    for (int p2 = 0; p2 < SPL; p2++)
      #pragma unroll
      for (int nt = 0; nt < 4; nt++)
        bv[p2][nt] = *(const bf16x8*)&w_pl[p2][nt * 16 + cl][cg * 8];
    #pragma unroll
    for (int d = 0; d < SPL; d++)
      #pragma unroll
      for (int i2 = 0; i2 <= d; i2++) {
        #pragma unroll
        for (int nt = 0; nt < 4; nt++)
          acc[nt] = mfma_bf16(av[i2], bv[d - i2][nt], acc[nt]);
      }
    __syncthreads();
  }
  #undef GLOADD
  float ps[4], ps2[4];
  #pragma unroll
  for (int i = 0; i < 4; i++) { ps[i] = 0.f; ps2[i] = 0.f; }
  #pragma unroll
  for (int nt = 0; nt < 4; nt++) {
    #pragma unroll
    for (int i = 0; i < 4; i++) {
      int r = m0 + wid * 16 + cg * 4 + i;
      int c = n0 + nt * 16 + cl;
      float v = acc[nt][i];
      if (bias) v += bias[c];
      if (ACT == 1) v = fmaxf(v, 0.f);
      if (ACT == 2) v = 1.f / (1.f + __expf(-v));
      size_t oi = (size_t)r * N + c;
      float nv = ACC ? (O[oi] + v) : v;
      O[oi] = nv;
      if (OUT2) O2[oi] = nv;
      if (STATS) { ps[i] += nv; ps2[i] += nv * nv; }
    }
  }
  if (STATS) {
    #pragma unroll
    for (int i = 0; i < 4; i++) {
      #pragma unroll
      for (int off = 1; off < 16; off <<= 1) {
        ps[i] += __shfl_xor(ps[i], off);
        ps2[i] += __shfl_xor(ps2[i], off);
      }
    }
    if (cl == 0) {
      #pragma unroll
      for (int i = 0; i < 4; i++) {
        int r = m0 + wid * 16 + cg * 4 + i;
        pout[r * 16 + blockIdx.x * 2] = ps[i];
        pout[r * 16 + blockIdx.x * 2 + 1] = ps2[i];
      }
    }
  }
}

// ------- Fused QKV + gate GEMM (2-split), LN-from-partials. 32x64 tile. -------
__global__ __launch_bounds__(128) void gemm_qkvg_kernel(
    const float* __restrict__ A, const float* __restrict__ pin,
    const float* __restrict__ lng, const float* __restrict__ lnb,
    const float* __restrict__ wqkv, const float* __restrict__ wg,
    const float* __restrict__ bg, float* __restrict__ qkv, float* __restrict__ gbuf) {
  __shared__ __align__(16) u16 a_pl[2][32][40];
  __shared__ __align__(16) u16 w_pl[2][64][40];
  const int n0 = blockIdx.x * 64, m0 = blockIdx.y * 32;
  const bool isg = (n0 >= 1152);
  const float* W = isg ? (wg + (size_t)(n0 - 1152) * 384) : (wqkv + (size_t)n0 * 384);
  const int t = threadIdx.x;
  const int wid = t >> 6, lane = t & 63;
  const int cl = lane & 15, cg = lane >> 4;
  const int ar = t >> 2, aq = t & 3;
  const int wr = t >> 1, wh = t & 1;
  const float* ap = A + (size_t)(m0 + ar) * 384 + aq * 8;
  const float* wp = W + (size_t)wr * 384 + wh * 16;
  float s = 0.f, s2 = 0.f;
  #pragma unroll
  for (int pq = 0; pq < 6; pq++) {
    s  += pin[(m0 + ar) * 16 + pq * 2];
    s2 += pin[(m0 + ar) * 16 + pq * 2 + 1];
  }
  const float rm = s * (1.f / 384.f);
  const float rrs = rsqrtf(s2 * (1.f / 384.f) - rm * rm + 1e-5f);
  float4 ra0, ra1, rw0, rw1, rw2, rw3, rg0, rg1, rb0, rb1;
  #define GLOADQ(k0) do { \
    ra0 = ((const float4*)(ap + (k0)))[0]; ra1 = ((const float4*)(ap + (k0)))[1]; \
    rw0 = ((const float4*)(wp + (k0)))[0]; rw1 = ((const float4*)(wp + (k0)))[1]; \
    rw2 = ((const float4*)(wp + (k0)))[2]; rw3 = ((const float4*)(wp + (k0)))[3]; \
    rg0 = ((const float4*)(lng + (k0) + aq * 8))[0]; rg1 = ((const float4*)(lng + (k0) + aq * 8))[1]; \
    rb0 = ((const float4*)(lnb + (k0) + aq * 8))[0]; rb1 = ((const float4*)(lnb + (k0) + aq * 8))[1]; \
  } while (0)
  GLOADQ(0);
  f32x4 acc[4] = {};
  for (int k0 = 0; k0 < 384; k0 += 32) {
    {
      float av[8] = {ra0.x, ra0.y, ra0.z, ra0.w, ra1.x, ra1.y, ra1.z, ra1.w};
      float gv[8] = {rg0.x, rg0.y, rg0.z, rg0.w, rg1.x, rg1.y, rg1.z, rg1.w};
      float bv[8] = {rb0.x, rb0.y, rb0.z, rb0.w, rb1.x, rb1.y, rb1.z, rb1.w};
      union { u16 s[8]; uint4 u; } ph, pl;
      #pragma unroll
      for (int j = 0; j < 8; j++) {
        float x = (av[j] - rm) * rrs * gv[j] + bv[j];
        split2(x, ph.s[j], pl.s[j]);
      }
      *(uint4*)&a_pl[0][ar][aq * 8] = ph.u;
      *(uint4*)&a_pl[1][ar][aq * 8] = pl.u;
      float wv[16] = {rw0.x, rw0.y, rw0.z, rw0.w, rw1.x, rw1.y, rw1.z, rw1.w,
                      rw2.x, rw2.y, rw2.z, rw2.w, rw3.x, rw3.y, rw3.z, rw3.w};
      #pragma unroll
      for (int hlf = 0; hlf < 2; hlf++) {
        #pragma unroll
        for (int j = 0; j < 8; j++) split2(wv[hlf * 8 + j], ph.s[j], pl.s[j]);
        *(uint4*)&w_pl[0][wr][wh * 16 + hlf * 8] = ph.u;
        *(uint4*)&w_pl[1][wr][wh * 16 + hlf * 8] = pl.u;
      }
    }
    __syncthreads();
    if (k0 + 32 < 384) GLOADQ(k0 + 32);
    bf16x8 ah = *(const bf16x8*)&a_pl[0][wid * 16 + cl][cg * 8];
    bf16x8 al = *(const bf16x8*)&a_pl[1][wid * 16 + cl][cg * 8];
    bf16x8 bh[4], bl[4];
    #pragma unroll
    for (int nt = 0; nt < 4; nt++) {
      bh[nt] = *(const bf16x8*)&w_pl[0][nt * 16 + cl][cg * 8];
      bl[nt] = *(const bf16x8*)&w_pl[1][nt * 16 + cl][cg * 8];
    }
    #pragma unroll
    for (int nt = 0; nt < 4; nt++) acc[nt] = mfma_bf16(ah, bh[nt], acc[nt]);
    #pragma unroll
    for (int nt = 0; nt < 4; nt++) acc[nt] = mfma_bf16(ah, bl[nt], acc[nt]);
    #pragma unroll
    for (int nt = 0; nt < 4; nt++) acc[nt] = mfma_bf16(al, bh[nt], acc[nt]);
    __syncthreads();
  }
  #undef GLOADQ
  #pragma unroll
  for (int nt = 0; nt < 4; nt++) {
    #pragma unroll
    for (int i = 0; i < 4; i++) {
      int r = m0 + wid * 16 + cg * 4 + i;
      int c = n0 + nt * 16 + cl;
      float v = acc[nt][i];
      if (isg) {
        int cc = c - 1152;
        v = 1.f / (1.f + __expf(-(v + bg[cc])));
        gbuf[(size_t)r * 384 + cc] = v;
      } else {
        qkv[(size_t)r * 1152 + c] = v;
      }
    }
  }
}

// ------- Fused LN(z) + z@w_b^T -> bmat fp32; 512 threads, pipelined 8 j-tiles -------
__global__ __launch_bounds__(512) void zbmat_kernel(
    const float* __restrict__ z, const float* __restrict__ gamma,
    const float* __restrict__ beta, const float* __restrict__ wb,
    const float* __restrict__ bbias, float* __restrict__ bm) {
  __shared__ __align__(16) u16 w_h[96][136], w_l[96][136];
  __shared__ __align__(16) u16 a_h[2][64][136], a_l[2][64][136];
  const int b = blockIdx.x >> 9;
  const int i = blockIdx.x & 511;
  const int t = threadIdx.x;
  for (int idx = t; idx < 96 * 128; idx += 512) {
    u16 h, l; split2(wb[idx], h, l);
    w_h[idx >> 7][idx & 127] = h;
    w_l[idx >> 7][idx & 127] = l;
  }
  const int r = t >> 3, q = t & 7;
  const int cq = q * 16;
  const float* zbase = z + ((size_t)(b * 512 + i) * 512) * 128 + (size_t)r * 128 + cq;
  float4 gv[4], bv[4];
  #pragma unroll
  for (int ii = 0; ii < 4; ii++) {
    gv[ii] = *(const float4*)(gamma + cq + ii * 4);
    bv[ii] = *(const float4*)(beta + cq + ii * 4);
  }
  const int wid = t >> 6, lane = t & 63;
  const int cl = lane & 15, cg = lane >> 4;
  const int m = wid & 3, g = wid >> 2;
  const int arow = m * 16 + cl;
  float bb[3];
  #pragma unroll
  for (int nt = 0; nt < 3; nt++) bb[nt] = bbias[(g * 3 + nt) * 16 + cl];
  float4 v[4];

  auto ln_store = [&](int dst) {
    float s = 0.f, s2 = 0.f;
    #pragma unroll
    for (int ii = 0; ii < 4; ii++) {
      s += v[ii].x + v[ii].y + v[ii].z + v[ii].w;
      s2 += v[ii].x * v[ii].x + v[ii].y * v[ii].y + v[ii].z * v[ii].z + v[ii].w * v[ii].w;
    }
    s += __shfl_xor(s, 1); s2 += __shfl_xor(s2, 1);
    s += __shfl_xor(s, 2); s2 += __shfl_xor(s2, 2);
    s += __shfl_xor(s, 4); s2 += __shfl_xor(s2, 4);
    const float mu = s * (1.f / 128.f);
    const float var = s2 * (1.f / 128.f) - mu * mu;
    const float rs = rsqrtf(var + 1e-5f);
    float xv[16];
    #pragma unroll
    for (int w2 = 0; w2 < 4; w2++) {
      float4 x = v[w2], g2 = gv[w2], be = bv[w2];
      xv[w2 * 4 + 0] = (x.x - mu) * rs * g2.x + be.x;
      xv[w2 * 4 + 1] = (x.y - mu) * rs * g2.y + be.y;
      xv[w2 * 4 + 2] = (x.z - mu) * rs * g2.z + be.z;
      xv[w2 * 4 + 3] = (x.w - mu) * rs * g2.w + be.w;
    }
    union { u16 s[8]; uint4 u; } ph, pl;
    #pragma unroll
    for (int j = 0; j < 8; j++) split2(xv[j], ph.s[j], pl.s[j]);
    *(uint4*)&a_h[dst][r][cq] = ph.u;
    *(uint4*)&a_l[dst][r][cq] = pl.u;
    #pragma unroll
    for (int j = 0; j < 8; j++) split2(xv[8 + j], ph.s[j], pl.s[j]);
    *(uint4*)&a_h[dst][r][cq + 8] = ph.u;
    *(uint4*)&a_l[dst][r][cq + 8] = pl.u;
  };

  #pragma unroll
  for (int ii = 0; ii < 4; ii++) v[ii] = ((const float4*)zbase)[ii];
  ln_store(0);
  __syncthreads();

  int cur = 0;
  for (int jt = 0; jt < 8; jt++) {
    if (jt < 7) {
      const float* src = zbase + (size_t)(jt + 1) * 64 * 128;
      #pragma unroll
      for (int ii = 0; ii < 4; ii++) v[ii] = ((const float4*)src)[ii];
    }
    f32x4 acc[3] = {};
    #pragma unroll
    for (int ks = 0; ks < 4; ks++) {
      bf16x8 ah = *(const bf16x8*)&a_h[cur][arow][ks * 32 + cg * 8];
      bf16x8 al = *(const bf16x8*)&a_l[cur][arow][ks * 32 + cg * 8];
      bf16x8 bh[3], bl[3];
      #pragma unroll
      for (int nt = 0; nt < 3; nt++) {
        bh[nt] = *(const bf16x8*)&w_h[(g * 3 + nt) * 16 + cl][ks * 32 + cg * 8];
        bl[nt] = *(const bf16x8*)&w_l[(g * 3 + nt) * 16 + cl][ks * 32 + cg * 8];
      }
      #pragma unroll
      for (int nt = 0; nt < 3; nt++) acc[nt] = mfma_bf16(ah, bh[nt], acc[nt]);
      #pragma unroll
      for (int nt = 0; nt < 3; nt++) acc[nt] = mfma_bf16(ah, bl[nt], acc[nt]);
      #pragma unroll
      for (int nt = 0; nt < 3; nt++) acc[nt] = mfma_bf16(al, bh[nt], acc[nt]);
    }
    #pragma unroll
    for (int nt = 0; nt < 3; nt++) {
      float4 o;
      o.x = acc[nt][0] + bb[nt]; o.y = acc[nt][1] + bb[nt];
      o.z = acc[nt][2] + bb[nt]; o.w = acc[nt][3] + bb[nt];
      int ch = (g * 3 + nt) * 16 + cl;
      *(float4*)&bm[((size_t)(b * 96 + ch) * 512 + i) * 512 + jt * 64 + m * 16 + cg * 4] = o;
    }
    if (jt < 7) ln_store(cur ^ 1);
    __syncthreads();
    cur ^= 1;
  }
}

// ---------------- Fused attention (one layer), 2-way split precision ----------------
__global__ __launch_bounds__(128) void attn_kernel(
    const float* __restrict__ qkv, const float* __restrict__ bmat,
    const int* __restrict__ maskp, const float* __restrict__ gate,
    float* __restrict__ ybuf, int layer) {
  __shared__ __align__(16) u16 vT_h[32][520];
  __shared__ __align__(16) u16 vT_l[32][520];
  __shared__ __align__(16) u16 pst_h[2][16][32];
  __shared__ __align__(16) u16 pst_l[2][16][32];
  const int bid = blockIdx.x;
  const int qb = bid & 15;
  const int h = (bid >> 4) % 12;
  const int b = bid / 192;
  const int q0 = qb * 32;
  const int t = threadIdx.x;
  const int wid = t >> 6;
  const int lane = t & 63;
  const int cl = lane & 15, cg = lane >> 4;

  for (int idx = t; idx < 512 * 8; idx += 128) {
    int k = idx >> 3, c4 = (idx & 7) << 2;
    const float* vp = qkv + (size_t)(b * 512 + k) * 1152 + h * 96 + 64 + c4;
    float4 vv = *(const float4*)vp;
    float va[4] = {vv.x, vv.y, vv.z, vv.w};
    #pragma unroll
    for (int j = 0; j < 4; j++) {
      u16 hh, ll; split2(va[j], hh, ll);
      vT_h[c4 + j][k] = hh;
      vT_l[c4 + j][k] = ll;
    }
  }

  const int qrow = q0 + wid * 16 + cl;
  const float* qp = qkv + (size_t)(b * 512 + qrow) * 1152 + h * 96 + cg * 8;
  float4 qv0 = ((const float4*)qp)[0];
  float4 qv1 = ((const float4*)qp)[1];
  const float qs = 0.17677669529663687f;
  float qa[8] = {qv0.x, qv0.y, qv0.z, qv0.w, qv1.x, qv1.y, qv1.z, qv1.w};
  union { u16 s[8]; bf16x8 v; } qh, ql;
  #pragma unroll
  for (int j = 0; j < 8; j++) split2(qa[j] * qs, qh.s[j], ql.s[j]);

  __syncthreads();

  const f32x4 zero4 = {0.f, 0.f, 0.f, 0.f};
  f32x4 sc[32];
  #pragma unroll
  for (int nt = 0; nt < 32; nt++) {
    int kk = nt * 16 + cl;
    const float* kp = qkv + (size_t)(b * 512 + kk) * 1152 + h * 96 + 32 + cg * 8;
    float4 k0 = ((const float4*)kp)[0];
    float4 k1 = ((const float4*)kp)[1];
    float ka[8] = {k0.x, k0.y, k0.z, k0.w, k1.x, k1.y, k1.z, k1.w};
    union { u16 s[8]; bf16x8 v; } kh, kl;
    #pragma unroll
    for (int j = 0; j < 8; j++) split2(ka[j], kh.s[j], kl.s[j]);
    f32x4 a = mfma_bf16(qh.v, kh.v, zero4);
    a = mfma_bf16(qh.v, kl.v, a);
    a = mfma_bf16(ql.v, kh.v, a);
    sc[nt] = a;
  }

  const size_t bc = (size_t)(b * 96 + layer * 12 + h);
  #pragma unroll
  for (int nt = 0; nt < 32; nt++) {
    int kk = nt * 16 + cl;
    int mk = maskp[b * 512 + kk];
    #pragma unroll
    for (int i2 = 0; i2 < 4; i2++) {
      int qq = q0 + wid * 16 + cg * 4 + i2;
      float bias = bmat[(bc * 512 + qq) * 512 + kk];
      float vv = sc[nt][i2] + bias;
      sc[nt][i2] = (mk == 0) ? -1e9f : vv;
    }
  }

  float inv[4];
  #pragma unroll
  for (int i2 = 0; i2 < 4; i2++) {
    float mx = -3e38f;
    #pragma unroll
    for (int nt = 0; nt < 32; nt++) mx = fmaxf(mx, sc[nt][i2]);
    mx = fmaxf(mx, __shfl_xor(mx, 1));
    mx = fmaxf(mx, __shfl_xor(mx, 2));
    mx = fmaxf(mx, __shfl_xor(mx, 4));
    mx = fmaxf(mx, __shfl_xor(mx, 8));
    float ss = 0.f;
    #pragma unroll
    for (int nt = 0; nt < 32; nt++) {
      float p = __expf(sc[nt][i2] - mx);
      sc[nt][i2] = p;
      ss += p;
    }
    ss += __shfl_xor(ss, 1);
    ss += __shfl_xor(ss, 2);
    ss += __shfl_xor(ss, 4);
    ss += __shfl_xor(ss, 8);
    inv[i2] = 1.f / ss;
  }

  f32x4 yacc[2] = {};
  for (int ks = 0; ks < 16; ks++) {
    #pragma unroll
    for (int half = 0; half < 2; half++) {
      int nt = ks * 2 + half;
      #pragma unroll
      for (int i2 = 0; i2 < 4; i2++) {
        u16 hh, ll; split2(sc[nt][i2] * inv[i2], hh, ll);
        pst_h[wid][cg * 4 + i2][half * 16 + cl] = hh;
        pst_l[wid][cg * 4 + i2][half * 16 + cl] = ll;
      }
    }
    __syncthreads();
    bf16x8 ph = *(const bf16x8*)&pst_h[wid][cl][cg * 8];
    bf16x8 pl = *(const bf16x8*)&pst_l[wid][cl][cg * 8];
    #pragma unroll
    for (int nt2 = 0; nt2 < 2; nt2++) {
      bf16x8 vh = *(const bf16x8*)&vT_h[nt2 * 16 + cl][ks * 32 + cg * 8];
      bf16x8 vl = *(const bf16x8*)&vT_l[nt2 * 16 + cl][ks * 32 + cg * 8];
      yacc[nt2] = mfma_bf16(ph, vh, yacc[nt2]);
      yacc[nt2] = mfma_bf16(ph, vl, yacc[nt2]);
      yacc[nt2] = mfma_bf16(pl, vh, yacc[nt2]);
    }
    __syncthreads();
  }

  #pragma unroll
  for (int nt2 = 0; nt2 < 2; nt2++) {
    #pragma unroll
    for (int i2 = 0; i2 < 4; i2++) {
      int qq = q0 + wid * 16 + cg * 4 + i2;
      int c = nt2 * 16 + cl;
      size_t oi = (size_t)(b * 512 + qq) * 384 + h * 32 + c;
      ybuf[oi] = yacc[nt2][i2] * gate[oi];
    }
  }
}

__device__ __forceinline__ void m3m(float* o, const float* a, const float* b) {
  #pragma unroll
  for (int i = 0; i < 3; i++)
    #pragma unroll
    for (int j = 0; j < 3; j++)
      o[i * 3 + j] = a[i * 3 + 0] * b[0 * 3 + j] + a[i * 3 + 1] * b[1 * 3 + j] + a[i * 3 + 2] * b[2 * 3 + j];
}
__device__ __forceinline__ void m3v(float* o, const float* a, const float* v) {
  #pragma unroll
  for (int i = 0; i < 3; i++)
    o[i] = a[i * 3 + 0] * v[0] + a[i * 3 + 1] * v[1] + a[i * 3 + 2] * v[2];
}

// -------- fused tail: w_bb matvec + ar_wout matvec + angles + rigid + frames + atoms --------
__global__ __launch_bounds__(256) void tail_kernel(
    const float* __restrict__ s_cur, const float* __restrict__ abuf,
    const float* __restrict__ w_bb, const float* __restrict__ b_bb,
    const float* __restrict__ ar_wout, const float* __restrict__ ar_bout,
    const int* __restrict__ aatype, const float* __restrict__ deff,
    const int* __restrict__ gidx, const float* __restrict__ amask,
    const float* __restrict__ lit,
    float* __restrict__ o_ang, float* __restrict__ o_un,
    float* __restrict__ o_bb4, float* __restrict__ o_rg4, float* __restrict__ o_pred) {
  int idx = blockIdx.x * 256 + threadIdx.x;
  if (idx >= 1024) return;
  // --- backbone 9-dim projection ---
  float p9[9];
  {
    const float* a = s_cur + (size_t)idx * 384;
    #pragma unroll
    for (int n = 0; n < 9; n++) {
      const float* w = w_bb + n * 384;
      float s = b_bb[n];
      for (int k = 0; k < 384; k++) s += a[k] * w[k];
      p9[n] = s;
    }
  }
  // --- angle head ---
  float ang[14];
  {
    const float* a = abuf + (size_t)idx * 128;
    float ar[128];
    for (int k = 0; k < 128; k++) ar[k] = fmaxf(a[k], 0.f);
    #pragma unroll
    for (int n = 0; n < 14; n++) {
      const float* w = ar_wout + n * 128;
      float s = ar_bout[n];
      for (int k = 0; k < 128; k++) s += ar[k] * w[k];
      ang[n] = s;
    }
  }
  #pragma unroll
  for (int a = 0; a < 7; a++) {
    float s0 = ang[a * 2], s1 = ang[a * 2 + 1];
    o_un[(idx * 7 + a) * 2] = s0; o_un[(idx * 7 + a) * 2 + 1] = s1;
    float d = sqrtf(fmaxf(s0 * s0 + s1 * s1, 1e-8f));
    ang[a * 2] = s0 / d; ang[a * 2 + 1] = s1 / d;
    o_ang[(idx * 7 + a) * 2] = ang[a * 2]; o_ang[(idx * 7 + a) * 2 + 1] = ang[a * 2 + 1];
  }
  // --- make_rigid ---
  float nx = p9[0] - p9[3], ny = p9[1] - p9[4], nz = p9[2] - p9[5];
  float cx = p9[6] - p9[3], cy = p9[7] - p9[4], cz = p9[8] - p9[5];
  const float eps = 1e-7f;
  float nrm = sqrtf(eps + cx * cx + cy * cy);
  float s1 = -cy / nrm, c1 = cx / nrm;
  float nrm2 = sqrtf(eps + cx * cx + cy * cy + cz * cz);
  float s2 = cz / nrm2, c2 = sqrtf(cx * cx + cy * cy) / nrm2;
  float Rc[9] = { c2 * c1, -c2 * s1, s2,
                  s1,      c1,       0.f,
                  -s2 * c1, s2 * s1, c2 };
  float n2y = Rc[3] * nx + Rc[4] * ny + Rc[5] * nz;
  float n2z = Rc[6] * nx + Rc[7] * ny + Rc[8] * nz;
  float nrm3 = sqrtf(eps + n2y * n2y + n2z * n2z);
  float sn = -n2z / nrm3, cn = n2y / nrm3;
  float Rm[9];
  Rm[0] = Rc[0]; Rm[1] = Rc[1]; Rm[2] = Rc[2];
  Rm[3] = cn * Rc[3] - sn * Rc[6];
  Rm[4] = cn * Rc[4] - sn * Rc[7];
  Rm[5] = cn * Rc[5] - sn * Rc[8];
  Rm[6] = sn * Rc[3] + cn * Rc[6];
  Rm[7] = sn * Rc[4] + cn * Rc[7];
  Rm[8] = sn * Rc[5] + cn * Rc[8];
  float Rb[9] = { Rm[0], Rm[3], Rm[6],
                  Rm[1], Rm[4], Rm[7],
                  Rm[2], Rm[5], Rm[8] };
  float tb[3] = { p9[3] * 10.f, p9[4] * 10.f, p9[5] * 10.f };
  {
    float* o = o_bb4 + (size_t)idx * 16;
    o[0] = Rb[0]; o[1] = Rb[1]; o[2] = Rb[2]; o[3] = tb[0];
    o[4] = Rb[3]; o[5] = Rb[4]; o[6] = Rb[5]; o[7] = tb[1];
    o[8] = Rb[6]; o[9] = Rb[7]; o[10] = Rb[8]; o[11] = tb[2];
    o[12] = 0.f; o[13] = 0.f; o[14] = 0.f; o[15] = 1.f;
  }
  // --- frames ---
  int aa = aatype[idx];
  float Rf[8][9], tf[8][3];
  for (int g = 0; g < 8; g++) {
    const float* d4 = deff + ((size_t)aa * 8 + g) * 16;
    float sa = 0.f, ca = 1.f;
    if (g > 0) { sa = ang[(g - 1) * 2]; ca = ang[(g - 1) * 2 + 1]; }
    #pragma unroll
    for (int i = 0; i < 3; i++) {
      float d0 = d4[i * 4 + 0], d1 = d4[i * 4 + 1], d2 = d4[i * 4 + 2];
      Rf[g][i * 3 + 0] = d0;
      Rf[g][i * 3 + 1] = d1 * ca + d2 * sa;
      Rf[g][i * 3 + 2] = -d1 * sa + d2 * ca;
      tf[g][i] = d4[i * 4 + 3];
    }
  }
  float Rall[8][9], tall[8][3];
  for (int g = 0; g < 5; g++) {
    #pragma unroll
    for (int i = 0; i < 9; i++) Rall[g][i] = Rf[g][i];
    #pragma unroll
    for (int i = 0; i < 3; i++) tall[g][i] = tf[g][i];
  }
  m3m(Rall[5], Rf[4], Rf[5]); m3v(tall[5], Rf[4], tf[5]);
  tall[5][0] += tf[4][0]; tall[5][1] += tf[4][1]; tall[5][2] += tf[4][2];
  m3m(Rall[6], Rall[5], Rf[6]); m3v(tall[6], Rall[5], tf[6]);
  tall[6][0] += tall[5][0]; tall[6][1] += tall[5][1]; tall[6][2] += tall[5][2];
  m3m(Rall[7], Rall[6], Rf[7]); m3v(tall[7], Rall[6], tf[7]);
  tall[7][0] += tall[6][0]; tall[7][1] += tall[6][1]; tall[7][2] += tall[6][2];
  float RG[8][9], TG[8][3];
  for (int g = 0; g < 8; g++) {
    m3m(RG[g], Rb, Rall[g]);
    m3v(TG[g], Rb, tall[g]);
    TG[g][0] += tb[0]; TG[g][1] += tb[1]; TG[g][2] += tb[2];
    float* o = o_rg4 + ((size_t)idx * 8 + g) * 16;
    o[0] = RG[g][0]; o[1] = RG[g][1]; o[2] = RG[g][2]; o[3] = TG[g][0];
    o[4] = RG[g][3]; o[5] = RG[g][4]; o[6] = RG[g][5]; o[7] = TG[g][1];
    o[8] = RG[g][6]; o[9] = RG[g][7]; o[10] = RG[g][8]; o[11] = TG[g][2];
    o[12] = 0.f; o[13] = 0.f; o[14] = 0.f; o[15] = 1.f;
  }
  for (int a = 0; a < 14; a++) {
    int gi = gidx[aa * 14 + a];
    const float* lp = lit + ((size_t)aa * 14 + a) * 3;
    float mk = amask[aa * 14 + a];
    float px = RG[gi][0] * lp[0] + RG[gi][1] * lp[1] + RG[gi][2] * lp[2] + TG[gi][0];
    float py = RG[gi][3] * lp[0] + RG[gi][4] * lp[1] + RG[gi][5] * lp[2] + TG[gi][1];
    float pz = RG[gi][6] * lp[0] + RG[gi][7] * lp[1] + RG[gi][8] * lp[2] + TG[gi][2];
    float* op = o_pred + ((size_t)idx * 14 + a) * 3;
    op[0] = px * mk; op[1] = py * mk; op[2] = pz * mk;
  }
}

extern "C" void kernel_launch(void* const* d_in, const int* in_sizes, int n_in,
                              void* d_out, int out_size, void* d_ws, size_t ws_size,
                              hipStream_t stream) {
  (void)in_sizes; (void)n_in; (void)out_size; (void)ws_size;
  const float* s_in    = (const float*)d_in[0];
  const float* z_in    = (const float*)d_in[1];
  const int*   aatype  = (const int*)d_in[2];
  const int*   maskp   = (const int*)d_in[3];
  const float* ln_s_g  = (const float*)d_in[4];
  const float* ln_s_b  = (const float*)d_in[5];
  const float* ln_z_g  = (const float*)d_in[6];
  const float* ln_z_b  = (const float*)d_in[7];
  const float* w_in    = (const float*)d_in[8];
  const float* b_in    = (const float*)d_in[9];
  const float* w_b     = (const float*)d_in[10];
  const float* b_b     = (const float*)d_in[11];
  const float* attn_ln_g = (const float*)d_in[12];
  const float* attn_ln_b = (const float*)d_in[13];
  const float* attn_wqkv = (const float*)d_in[14];
  const float* attn_wo   = (const float*)d_in[15];
  const float* attn_bo   = (const float*)d_in[16];
  const float* attn_wg   = (const float*)d_in[17];
  const float* attn_bg   = (const float*)d_in[18];
  const float* tr_ln_g   = (const float*)d_in[19];
  const float* tr_ln_b   = (const float*)d_in[20];
  const float* tr_w1     = (const float*)d_in[21];
  const float* tr_b1     = (const float*)d_in[22];
  const float* tr_w2     = (const float*)d_in[23];
  const float* tr_b2     = (const float*)d_in[24];
  const float* w_bb      = (const float*)d_in[25];
  const float* b_bb      = (const float*)d_in[26];
  const float* ar_win    = (const float*)d_in[27];
  const float* ar_bin    = (const float*)d_in[28];
  const float* ar_winit  = (const float*)d_in[29];
  const float* ar_binit  = (const float*)d_in[30];
  const float* ar_w1     = (const float*)d_in[31];
  const float* ar_b1     = (const float*)d_in[32];
  const float* ar_w2     = (const float*)d_in[33];
  const float* ar_b2     = (const float*)d_in[34];
  const float* ar_wout   = (const float*)d_in[35];
  const float* ar_bout   = (const float*)d_in[36];
  const float* def_frames= (const float*)d_in[37];
  const int*   group_idx = (const int*)d_in[38];
  const float* atom_mask = (const float*)d_in[39];
  const float* lit_pos   = (const float*)d_in[40];

  char* p = (char*)d_ws;
  float* bmat   = (float*)p;          p += 201326592;
  float* s_init = (float*)p;          p += 1572864;
  float* s_cur  = (float*)p;          p += 1572864;
  float* qkv    = (float*)p;          p += 4718592;
  float* gbuf   = (float*)p;          p += 1572864;
  float* ybuf   = (float*)p;          p += 1572864;
  float* h1buf  = (float*)p;          p += 1572864;
  float* abuf   = (float*)p;          p += 524288;
  float* htmp   = (float*)p;          p += 524288;
  float* pbuf   = (float*)p;          p += 65536;

  float* out    = (float*)d_out;
  float* o_ang  = out;
  float* o_un   = out + 14336;
  float* o_bb4  = out + 28672;
  float* o_rg4  = out + 45056;
  float* o_pred = out + 176128;
  float* o_s    = out + 219136;

  // s_init = LN(s)
  ln_kernel<<<256, 256, 0, stream>>>(s_in, ln_s_g, ln_s_b, s_init, 1024, 384);
  // s_cur = s_init @ w_in^T + b_in   (+row stats for layer-0 LN)
  gemm_kernel<2, 0, 0, 0, 0, 1, 0><<<dim3(6, 32), 128, 0, stream>>>(
      s_init, nullptr, nullptr, nullptr, w_in, b_in, s_cur, nullptr, pbuf, 1024, 384, 384);
  // bmat from z (fp32)
  zbmat_kernel<<<1024, 512, 0, stream>>>(z_in, ln_z_g, ln_z_b, w_b, b_b, bmat);

  for (int l = 0; l < 8; ++l) {
    gemm_qkvg_kernel<<<dim3(24, 32), 128, 0, stream>>>(
        s_cur, pbuf, attn_ln_g + l * 384, attn_ln_b + l * 384,
        attn_wqkv + (size_t)l * 442368, attn_wg + (size_t)l * 147456,
        attn_bg + l * 384, qkv, gbuf);
    attn_kernel<<<384, 128, 0, stream>>>(qkv, bmat, maskp, gbuf, ybuf, l);
    gemm_kernel<2, 0, 0, 0, 1, 1, 0><<<dim3(6, 32), 128, 0, stream>>>(
        ybuf, nullptr, nullptr, nullptr, attn_wo + (size_t)l * 147456,
        attn_bo + l * 384, s_cur, nullptr, pbuf, 1024, 384, 384);
    gemm_kernel<2, 2, 0, 1, 0, 0, 0><<<dim3(6, 32), 128, 0, stream>>>(
        s_cur, pbuf, tr_ln_g + l * 384, tr_ln_b + l * 384,
        tr_w1 + (size_t)l * 147456, tr_b1 + l * 384, h1buf, nullptr, nullptr, 1024, 384, 384);
    if (l < 7)
      gemm_kernel<2, 0, 0, 0, 1, 1, 0><<<dim3(6, 32), 128, 0, stream>>>(
          h1buf, nullptr, nullptr, nullptr, tr_w2 + (size_t)l * 147456,
          tr_b2 + l * 384, s_cur, nullptr, pbuf, 1024, 384, 384);
    else
      gemm_kernel<2, 0, 0, 0, 1, 1, 1><<<dim3(6, 32), 128, 0, stream>>>(
          h1buf, nullptr, nullptr, nullptr, tr_w2 + (size_t)l * 147456,
          tr_b2 + l * 384, s_cur, o_s, pbuf, 1024, 384, 384);
  }

  // angle resnet (3-split)
  gemm_kernel<3, 0, 1, 0, 0, 0, 0><<<dim3(2, 32), 128, 0, stream>>>(
      s_cur, nullptr, nullptr, nullptr, ar_win, ar_bin, abuf, nullptr, nullptr, 1024, 128, 384);
  gemm_kernel<3, 0, 1, 0, 1, 0, 0><<<dim3(2, 32), 128, 0, stream>>>(
      s_init, nullptr, nullptr, nullptr, ar_winit, ar_binit, abuf, nullptr, nullptr, 1024, 128, 384);
  for (int j = 0; j < 2; ++j) {
    gemm_kernel<3, 0, 1, 0, 0, 0, 0><<<dim3(2, 32), 128, 0, stream>>>(
        abuf, nullptr, nullptr, nullptr, ar_w1 + j * 16384, ar_b1 + j * 128, htmp, nullptr, nullptr, 1024, 128, 128);
    gemm_kernel<3, 0, 1, 0, 1, 0, 0><<<dim3(2, 32), 128, 0, stream>>>(
        htmp, nullptr, nullptr, nullptr, ar_w2 + j * 16384, ar_b2 + j * 128, abuf, nullptr, nullptr, 1024, 128, 128);
  }

  tail_kernel<<<4, 256, 0, stream>>>(s_cur, abuf, w_bb, b_bb, ar_wout, ar_bout,
                                     aatype, def_frames, group_idx, atom_mask, lit_pos,
                                     o_ang, o_un, o_bb4, o_rg4, o_pred);
}

// Round 5
// 1098.402 us; speedup vs baseline: 1.2927x; 1.2927x over previous
//
#include <hip/hip_runtime.h>
#include <hip/hip_bf16.h>

typedef __attribute__((ext_vector_type(8))) short bf16x8;
typedef __attribute__((ext_vector_type(4))) float f32x4;
typedef unsigned short u16;

__device__ __forceinline__ u16 f2bf(float f) {
  union { __hip_bfloat16 b; u16 u; } v;
  v.b = __float2bfloat16(f);
  return v.u;
}
__device__ __forceinline__ float bf2f(u16 s) {
  union { unsigned u; float f; } v; v.u = ((unsigned)s) << 16;
  return v.f;
}
__device__ __forceinline__ f32x4 mfma_bf16(bf16x8 a, bf16x8 b, f32x4 c) {
  return __builtin_amdgcn_mfma_f32_16x16x32_bf16(a, b, c, 0, 0, 0);
}
__device__ __forceinline__ void split2(float x, u16& h, u16& l) {
  h = f2bf(x);
  l = f2bf(x - bf2f(h));
}
template <int SPL>
__device__ __forceinline__ void splitN(float x, u16* o) {
  float r = x;
  #pragma unroll
  for (int i = 0; i < SPL; i++) {
    o[i] = f2bf(r);
    if (i + 1 < SPL) r = r - bf2f(o[i]);
  }
}

// ---------------- weight pre-split kernels (once per launch) ----------------
struct P2 { const float* s; u16* d; int n; };
struct Prep2Args { P2 j[7]; };
__global__ __launch_bounds__(256) void prep2_kernel(Prep2Args A, int total4) {
  for (int i4 = blockIdx.x * 256 + threadIdx.x; i4 < total4; i4 += gridDim.x * 256) {
    int i = i4 * 4;
    #pragma unroll
    for (int jj = 0; jj < 7; jj++) {
      if (i < A.j[jj].n) {
        const float* src = A.j[jj].s;
        u16* dh = A.j[jj].d;
        u16* dl = dh + A.j[jj].n;
        float4 v = *(const float4*)(src + i);
        ushort4 h, l;
        split2(v.x, h.x, l.x); split2(v.y, h.y, l.y);
        split2(v.z, h.z, l.z); split2(v.w, h.w, l.w);
        *(ushort4*)(dh + i) = h;
        *(ushort4*)(dl + i) = l;
        break;
      }
      i -= A.j[jj].n;
    }
  }
}
struct P3 { const float* s; u16* d; int n; };
struct Prep3Args { P3 j[4]; };
__global__ __launch_bounds__(256) void prep3_kernel(Prep3Args A, int total4) {
  for (int i4 = blockIdx.x * 256 + threadIdx.x; i4 < total4; i4 += gridDim.x * 256) {
    int i = i4 * 4;
    #pragma unroll
    for (int jj = 0; jj < 4; jj++) {
      if (i < A.j[jj].n) {
        const float* src = A.j[jj].s;
        u16* d0 = A.j[jj].d;
        u16* d1 = d0 + A.j[jj].n;
        u16* d2 = d1 + A.j[jj].n;
        float4 v = *(const float4*)(src + i);
        float xv[4] = {v.x, v.y, v.z, v.w};
        ushort4 o0, o1, o2;
        u16* po0 = (u16*)&o0; u16* po1 = (u16*)&o1; u16* po2 = (u16*)&o2;
        #pragma unroll
        for (int e = 0; e < 4; e++) {
          u16 tmp[3]; splitN<3>(xv[e], tmp);
          po0[e] = tmp[0]; po1[e] = tmp[1]; po2[e] = tmp[2];
        }
        *(ushort4*)(d0 + i) = o0;
        *(ushort4*)(d1 + i) = o1;
        *(ushort4*)(d2 + i) = o2;
        break;
      }
      i -= A.j[jj].n;
    }
  }
}

// ---------------- LayerNorm full output (fp32), one wave per row ----------------
__global__ __launch_bounds__(256) void ln_kernel(
    const float* __restrict__ x, const float* __restrict__ gamma,
    const float* __restrict__ beta, float* __restrict__ o, int rows, int C) {
  int wid = threadIdx.x >> 6, lane = threadIdx.x & 63;
  int row = blockIdx.x * 4 + wid;
  if (row >= rows) return;
  const float* xr = x + (size_t)row * C;
  float s = 0.f, s2 = 0.f;
  for (int c = lane; c < C; c += 64) { float v = xr[c]; s += v; s2 += v * v; }
  #pragma unroll
  for (int off = 32; off >= 1; off >>= 1) {
    s += __shfl_xor(s, off);
    s2 += __shfl_xor(s2, off);
  }
  float m = s / C;
  float var = s2 / C - m * m;
  float rs = rsqrtf(var + 1e-5f);
  float* orow = o + (size_t)row * C;
  for (int c = lane; c < C; c += 64) orow[c] = (xr[c] - m) * rs * gamma[c] + beta[c];
}

// ------- Dense GEMM with PRE-SPLIT weights. 32(M)x64(N) tile, 128 threads. -------
// LNA: LayerNorm A from row-partials pin (producer had 6 n-blocks).
// STATS: per-block row partials {sum,sumsq} of O into pout. OUT2: mirror O to O2.
template <int SPL, int LNA, int INRELU, int ACT, int ACC, int STATS, int OUT2>
__global__ __launch_bounds__(128) void gemm_kernel(
    const float* __restrict__ A, const float* __restrict__ pin,
    const float* __restrict__ lng, const float* __restrict__ lnb,
    const u16* __restrict__ w0p, const u16* __restrict__ w1p, const u16* __restrict__ w2p,
    const float* __restrict__ bias,
    float* __restrict__ O, float* __restrict__ O2, float* __restrict__ pout,
    int M, int N, int K) {
  __shared__ __align__(16) u16 a_pl[SPL][32][40];
  __shared__ __align__(16) u16 w_pl[SPL][64][40];
  const int n0 = blockIdx.x * 64, m0 = blockIdx.y * 32;
  const int t = threadIdx.x;
  const int wid = t >> 6, lane = t & 63;
  const int cl = lane & 15, cg = lane >> 4;
  const int ar = t >> 2, aq = t & 3;
  const int wr = t >> 1, wh2 = t & 1;
  const float* ap = A + (size_t)(m0 + ar) * K + aq * 8;
  const u16* wp[SPL];
  {
    const u16* tmp[3] = {w0p, w1p, w2p};
    #pragma unroll
    for (int p = 0; p < SPL; p++) wp[p] = tmp[p] + (size_t)(n0 + wr) * K + wh2 * 16;
  }
  float rm = 0.f, rrs = 1.f;
  if (LNA) {
    float s = 0.f, s2 = 0.f;
    #pragma unroll
    for (int pq = 0; pq < 6; pq++) {
      s  += pin[(m0 + ar) * 16 + pq * 2];
      s2 += pin[(m0 + ar) * 16 + pq * 2 + 1];
    }
    rm = s * (1.f / 384.f);
    rrs = rsqrtf(s2 * (1.f / 384.f) - rm * rm + 1e-5f);
  }
  float4 ra0, ra1, rg0, rg1, rb0, rb1;
  uint4 rw[SPL][2];
  auto GLOAD = [&](int k0) {
    ra0 = ((const float4*)(ap + k0))[0];
    ra1 = ((const float4*)(ap + k0))[1];
    #pragma unroll
    for (int p = 0; p < SPL; p++) {
      rw[p][0] = *(const uint4*)(wp[p] + k0);
      rw[p][1] = *(const uint4*)(wp[p] + k0 + 8);
    }
    if (LNA) {
      rg0 = ((const float4*)(lng + k0 + aq * 8))[0];
      rg1 = ((const float4*)(lng + k0 + aq * 8))[1];
      rb0 = ((const float4*)(lnb + k0 + aq * 8))[0];
      rb1 = ((const float4*)(lnb + k0 + aq * 8))[1];
    }
  };
  GLOAD(0);
  f32x4 acc[4] = {};
  for (int k0 = 0; k0 < K; k0 += 32) {
    {
      float av[8] = {ra0.x, ra0.y, ra0.z, ra0.w, ra1.x, ra1.y, ra1.z, ra1.w};
      if (LNA) {
        float gv[8] = {rg0.x, rg0.y, rg0.z, rg0.w, rg1.x, rg1.y, rg1.z, rg1.w};
        float bv[8] = {rb0.x, rb0.y, rb0.z, rb0.w, rb1.x, rb1.y, rb1.z, rb1.w};
        #pragma unroll
        for (int j = 0; j < 8; j++) av[j] = (av[j] - rm) * rrs * gv[j] + bv[j];
      }
      if (INRELU) {
        #pragma unroll
        for (int j = 0; j < 8; j++) av[j] = fmaxf(av[j], 0.f);
      }
      union { u16 s[8]; uint4 u; } pk[SPL];
      #pragma unroll
      for (int j = 0; j < 8; j++) {
        u16 tmp[SPL]; splitN<SPL>(av[j], tmp);
        #pragma unroll
        for (int p = 0; p < SPL; p++) pk[p].s[j] = tmp[p];
      }
      #pragma unroll
      for (int p = 0; p < SPL; p++) *(uint4*)&a_pl[p][ar][aq * 8] = pk[p].u;
      #pragma unroll
      for (int p = 0; p < SPL; p++) {
        *(uint4*)&w_pl[p][wr][wh2 * 16] = rw[p][0];
        *(uint4*)&w_pl[p][wr][wh2 * 16 + 8] = rw[p][1];
      }
    }
    __syncthreads();
    if (k0 + 32 < K) GLOAD(k0 + 32);
    bf16x8 av[SPL];
    #pragma unroll
    for (int p = 0; p < SPL; p++) av[p] = *(const bf16x8*)&a_pl[p][wid * 16 + cl][cg * 8];
    bf16x8 bv[SPL][4];
    #pragma unroll
    for (int p = 0; p < SPL; p++)
      #pragma unroll
      for (int nt = 0; nt < 4; nt++)
        bv[p][nt] = *(const bf16x8*)&w_pl[p][nt * 16 + cl][cg * 8];
    #pragma unroll
    for (int d = 0; d < SPL; d++)
      #pragma unroll
      for (int i2 = 0; i2 <= d; i2++) {
        #pragma unroll
        for (int nt = 0; nt < 4; nt++)
          acc[nt] = mfma_bf16(av[i2], bv[d - i2][nt], acc[nt]);
      }
    __syncthreads();
  }
  float ps[4], ps2[4];
  #pragma unroll
  for (int i = 0; i < 4; i++) { ps[i] = 0.f; ps2[i] = 0.f; }
  #pragma unroll
  for (int nt = 0; nt < 4; nt++) {
    #pragma unroll
    for (int i = 0; i < 4; i++) {
      int r = m0 + wid * 16 + cg * 4 + i;
      int c = n0 + nt * 16 + cl;
      float v = acc[nt][i];
      if (bias) v += bias[c];
      if (ACT == 1) v = fmaxf(v, 0.f);
      if (ACT == 2) v = 1.f / (1.f + __expf(-v));
      size_t oi = (size_t)r * N + c;
      float nv = ACC ? (O[oi] + v) : v;
      O[oi] = nv;
      if (OUT2) O2[oi] = nv;
      if (STATS) { ps[i] += nv; ps2[i] += nv * nv; }
    }
  }
  if (STATS) {
    #pragma unroll
    for (int i = 0; i < 4; i++) {
      #pragma unroll
      for (int off = 1; off < 16; off <<= 1) {
        ps[i] += __shfl_xor(ps[i], off);
        ps2[i] += __shfl_xor(ps2[i], off);
      }
    }
    if (cl == 0) {
      #pragma unroll
      for (int i = 0; i < 4; i++) {
        int r = m0 + wid * 16 + cg * 4 + i;
        pout[r * 16 + blockIdx.x * 2] = ps[i];
        pout[r * 16 + blockIdx.x * 2 + 1] = ps2[i];
      }
    }
  }
}

// ------- Fused QKV + gate GEMM (pre-split W, 2-split A, LN from partials). -------
// qkv written as bf16 hi/lo planes.
__global__ __launch_bounds__(128) void gemm_qkvg_kernel(
    const float* __restrict__ A, const float* __restrict__ pin,
    const float* __restrict__ lng, const float* __restrict__ lnb,
    const u16* __restrict__ wqh, const u16* __restrict__ wql,
    const u16* __restrict__ wgh, const u16* __restrict__ wgl,
    const float* __restrict__ bg,
    u16* __restrict__ qkvh, u16* __restrict__ qkvl, float* __restrict__ gbuf) {
  __shared__ __align__(16) u16 a_pl[2][32][40];
  __shared__ __align__(16) u16 w_pl[2][64][40];
  const int n0 = blockIdx.x * 64, m0 = blockIdx.y * 32;
  const bool isg = (n0 >= 1152);
  const int t = threadIdx.x;
  const int wid = t >> 6, lane = t & 63;
  const int cl = lane & 15, cg = lane >> 4;
  const int ar = t >> 2, aq = t & 3;
  const int wr = t >> 1, wh2 = t & 1;
  const float* ap = A + (size_t)(m0 + ar) * 384 + aq * 8;
  const u16* wph = (isg ? wgh + (size_t)(n0 - 1152 + wr) * 384 : wqh + (size_t)(n0 + wr) * 384) + wh2 * 16;
  const u16* wpl = (isg ? wgl + (size_t)(n0 - 1152 + wr) * 384 : wql + (size_t)(n0 + wr) * 384) + wh2 * 16;
  float s = 0.f, s2 = 0.f;
  #pragma unroll
  for (int pq = 0; pq < 6; pq++) {
    s  += pin[(m0 + ar) * 16 + pq * 2];
    s2 += pin[(m0 + ar) * 16 + pq * 2 + 1];
  }
  const float rm = s * (1.f / 384.f);
  const float rrs = rsqrtf(s2 * (1.f / 384.f) - rm * rm + 1e-5f);
  float4 ra0, ra1, rg0, rg1, rb0, rb1;
  uint4 rwh0, rwh1, rwl0, rwl1;
  auto GLOAD = [&](int k0) {
    ra0 = ((const float4*)(ap + k0))[0];
    ra1 = ((const float4*)(ap + k0))[1];
    rwh0 = *(const uint4*)(wph + k0);
    rwh1 = *(const uint4*)(wph + k0 + 8);
    rwl0 = *(const uint4*)(wpl + k0);
    rwl1 = *(const uint4*)(wpl + k0 + 8);
    rg0 = ((const float4*)(lng + k0 + aq * 8))[0];
    rg1 = ((const float4*)(lng + k0 + aq * 8))[1];
    rb0 = ((const float4*)(lnb + k0 + aq * 8))[0];
    rb1 = ((const float4*)(lnb + k0 + aq * 8))[1];
  };
  GLOAD(0);
  f32x4 acc[4] = {};
  for (int k0 = 0; k0 < 384; k0 += 32) {
    {
      float av[8] = {ra0.x, ra0.y, ra0.z, ra0.w, ra1.x, ra1.y, ra1.z, ra1.w};
      float gv[8] = {rg0.x, rg0.y, rg0.z, rg0.w, rg1.x, rg1.y, rg1.z, rg1.w};
      float bv[8] = {rb0.x, rb0.y, rb0.z, rb0.w, rb1.x, rb1.y, rb1.z, rb1.w};
      union { u16 s[8]; uint4 u; } ph, pl;
      #pragma unroll
      for (int j = 0; j < 8; j++) {
        float x = (av[j] - rm) * rrs * gv[j] + bv[j];
        split2(x, ph.s[j], pl.s[j]);
      }
      *(uint4*)&a_pl[0][ar][aq * 8] = ph.u;
      *(uint4*)&a_pl[1][ar][aq * 8] = pl.u;
      *(uint4*)&w_pl[0][wr][wh2 * 16] = rwh0;
      *(uint4*)&w_pl[0][wr][wh2 * 16 + 8] = rwh1;
      *(uint4*)&w_pl[1][wr][wh2 * 16] = rwl0;
      *(uint4*)&w_pl[1][wr][wh2 * 16 + 8] = rwl1;
    }
    __syncthreads();
    if (k0 + 32 < 384) GLOAD(k0 + 32);
    bf16x8 ah = *(const bf16x8*)&a_pl[0][wid * 16 + cl][cg * 8];
    bf16x8 al = *(const bf16x8*)&a_pl[1][wid * 16 + cl][cg * 8];
    bf16x8 bh[4], bl[4];
    #pragma unroll
    for (int nt = 0; nt < 4; nt++) {
      bh[nt] = *(const bf16x8*)&w_pl[0][nt * 16 + cl][cg * 8];
      bl[nt] = *(const bf16x8*)&w_pl[1][nt * 16 + cl][cg * 8];
    }
    #pragma unroll
    for (int nt = 0; nt < 4; nt++) acc[nt] = mfma_bf16(ah, bh[nt], acc[nt]);
    #pragma unroll
    for (int nt = 0; nt < 4; nt++) acc[nt] = mfma_bf16(ah, bl[nt], acc[nt]);
    #pragma unroll
    for (int nt = 0; nt < 4; nt++) acc[nt] = mfma_bf16(al, bh[nt], acc[nt]);
    __syncthreads();
  }
  #pragma unroll
  for (int nt = 0; nt < 4; nt++) {
    #pragma unroll
    for (int i = 0; i < 4; i++) {
      int r = m0 + wid * 16 + cg * 4 + i;
      int c = n0 + nt * 16 + cl;
      float v = acc[nt][i];
      if (isg) {
        int cc = c - 1152;
        v = 1.f / (1.f + __expf(-(v + bg[cc])));
        gbuf[(size_t)r * 384 + cc] = v;
      } else {
        u16 hh, ll; split2(v, hh, ll);
        qkvh[(size_t)r * 1152 + c] = hh;
        qkvl[(size_t)r * 1152 + c] = ll;
      }
    }
  }
}

// ------- Fused LN(z) + z@w_b^T -> bmat fp32; pre-split w_b; 512 thr; 8 j-tiles -------
__global__ __launch_bounds__(512) void zbmat_kernel(
    const float* __restrict__ z, const float* __restrict__ gamma,
    const float* __restrict__ beta, const u16* __restrict__ wbh,
    const u16* __restrict__ wbl, const float* __restrict__ bbias,
    float* __restrict__ bm) {
  __shared__ __align__(16) u16 w_h[96][136], w_l[96][136];
  __shared__ __align__(16) u16 a_h[2][64][136], a_l[2][64][136];
  const int b = blockIdx.x >> 9;
  const int i = blockIdx.x & 511;
  const int t = threadIdx.x;
  for (int idx = t; idx < 1536; idx += 512) {
    int r2 = idx >> 4, c2 = (idx & 15) * 8;
    *(uint4*)&w_h[r2][c2] = *(const uint4*)(wbh + r2 * 128 + c2);
    *(uint4*)&w_l[r2][c2] = *(const uint4*)(wbl + r2 * 128 + c2);
  }
  const int r = t >> 3, q = t & 7;
  const int cq = q * 16;
  const float* zbase = z + ((size_t)(b * 512 + i) * 512) * 128 + (size_t)r * 128 + cq;
  float4 gv[4], bv[4];
  #pragma unroll
  for (int ii = 0; ii < 4; ii++) {
    gv[ii] = *(const float4*)(gamma + cq + ii * 4);
    bv[ii] = *(const float4*)(beta + cq + ii * 4);
  }
  const int wid = t >> 6, lane = t & 63;
  const int cl = lane & 15, cg = lane >> 4;
  const int m = wid & 3, g = wid >> 2;
  const int arow = m * 16 + cl;
  float bb[3];
  #pragma unroll
  for (int nt = 0; nt < 3; nt++) bb[nt] = bbias[(g * 3 + nt) * 16 + cl];
  float4 v[4];

  auto ln_store = [&](int dst) {
    float s = 0.f, s2 = 0.f;
    #pragma unroll
    for (int ii = 0; ii < 4; ii++) {
      s += v[ii].x + v[ii].y + v[ii].z + v[ii].w;
      s2 += v[ii].x * v[ii].x + v[ii].y * v[ii].y + v[ii].z * v[ii].z + v[ii].w * v[ii].w;
    }
    s += __shfl_xor(s, 1); s2 += __shfl_xor(s2, 1);
    s += __shfl_xor(s, 2); s2 += __shfl_xor(s2, 2);
    s += __shfl_xor(s, 4); s2 += __shfl_xor(s2, 4);
    const float mu = s * (1.f / 128.f);
    const float var = s2 * (1.f / 128.f) - mu * mu;
    const float rs = rsqrtf(var + 1e-5f);
    float xv[16];
    #pragma unroll
    for (int w2 = 0; w2 < 4; w2++) {
      float4 x = v[w2], g2 = gv[w2], be = bv[w2];
      xv[w2 * 4 + 0] = (x.x - mu) * rs * g2.x + be.x;
      xv[w2 * 4 + 1] = (x.y - mu) * rs * g2.y + be.y;
      xv[w2 * 4 + 2] = (x.z - mu) * rs * g2.z + be.z;
      xv[w2 * 4 + 3] = (x.w - mu) * rs * g2.w + be.w;
    }
    union { u16 s[8]; uint4 u; } ph, pl;
    #pragma unroll
    for (int j = 0; j < 8; j++) split2(xv[j], ph.s[j], pl.s[j]);
    *(uint4*)&a_h[dst][r][cq] = ph.u;
    *(uint4*)&a_l[dst][r][cq] = pl.u;
    #pragma unroll
    for (int j = 0; j < 8; j++) split2(xv[8 + j], ph.s[j], pl.s[j]);
    *(uint4*)&a_h[dst][r][cq + 8] = ph.u;
    *(uint4*)&a_l[dst][r][cq + 8] = pl.u;
  };

  #pragma unroll
  for (int ii = 0; ii < 4; ii++) v[ii] = ((const float4*)zbase)[ii];
  ln_store(0);
  __syncthreads();

  int cur = 0;
  for (int jt = 0; jt < 8; jt++) {
    if (jt < 7) {
      const float* src = zbase + (size_t)(jt + 1) * 64 * 128;
      #pragma unroll
      for (int ii = 0; ii < 4; ii++) v[ii] = ((const float4*)src)[ii];
    }
    f32x4 acc[3] = {};
    #pragma unroll
    for (int ks = 0; ks < 4; ks++) {
      bf16x8 ah = *(const bf16x8*)&a_h[cur][arow][ks * 32 + cg * 8];
      bf16x8 al = *(const bf16x8*)&a_l[cur][arow][ks * 32 + cg * 8];
      bf16x8 bh[3], bl[3];
      #pragma unroll
      for (int nt = 0; nt < 3; nt++) {
        bh[nt] = *(const bf16x8*)&w_h[(g * 3 + nt) * 16 + cl][ks * 32 + cg * 8];
        bl[nt] = *(const bf16x8*)&w_l[(g * 3 + nt) * 16 + cl][ks * 32 + cg * 8];
      }
      #pragma unroll
      for (int nt = 0; nt < 3; nt++) acc[nt] = mfma_bf16(ah, bh[nt], acc[nt]);
      #pragma unroll
      for (int nt = 0; nt < 3; nt++) acc[nt] = mfma_bf16(ah, bl[nt], acc[nt]);
      #pragma unroll
      for (int nt = 0; nt < 3; nt++) acc[nt] = mfma_bf16(al, bh[nt], acc[nt]);
    }
    #pragma unroll
    for (int nt = 0; nt < 3; nt++) {
      float4 o;
      o.x = acc[nt][0] + bb[nt]; o.y = acc[nt][1] + bb[nt];
      o.z = acc[nt][2] + bb[nt]; o.w = acc[nt][3] + bb[nt];
      int ch = (g * 3 + nt) * 16 + cl;
      *(float4*)&bm[((size_t)(b * 96 + ch) * 512 + i) * 512 + jt * 64 + m * 16 + cg * 4] = o;
    }
    if (jt < 7) ln_store(cur ^ 1);
    __syncthreads();
    cur ^= 1;
  }
}

// ---------------- Fused attention (one layer); qkv from bf16 hi/lo planes ----------------
__global__ __launch_bounds__(128) void attn_kernel(
    const u16* __restrict__ qkvh, const u16* __restrict__ qkvl,
    const float* __restrict__ bmat, const int* __restrict__ maskp,
    const float* __restrict__ gate, float* __restrict__ ybuf, int layer) {
  __shared__ __align__(16) u16 vT_h[32][522];
  __shared__ __align__(16) u16 vT_l[32][522];
  __shared__ __align__(16) u16 pst_h[2][16][36];
  __shared__ __align__(16) u16 pst_l[2][16][36];
  const int bid = blockIdx.x;
  const int qb = bid & 15;
  const int hh = (bid >> 4) % 12;
  const int b = bid / 192;
  const int q0 = qb * 32;
  const int t = threadIdx.x;
  const int wid = t >> 6;
  const int lane = t & 63;
  const int cl = lane & 15, cg = lane >> 4;

  // stage V^T planes
  for (int idx = t; idx < 2048; idx += 128) {
    int k = idx >> 2, c8 = (idx & 3) * 8;
    size_t off = (size_t)(b * 512 + k) * 1152 + hh * 96 + 64 + c8;
    union { uint4 u; u16 s[8]; } vh, vl;
    vh.u = *(const uint4*)(qkvh + off);
    vl.u = *(const uint4*)(qkvl + off);
    #pragma unroll
    for (int j = 0; j < 8; j++) {
      vT_h[c8 + j][k] = vh.s[j];
      vT_l[c8 + j][k] = vl.s[j];
    }
  }

  const int qrow = q0 + wid * 16 + cl;
  const size_t qoff = (size_t)(b * 512 + qrow) * 1152 + hh * 96 + cg * 8;
  bf16x8 qh = *(const bf16x8*)(qkvh + qoff);
  bf16x8 ql = *(const bf16x8*)(qkvl + qoff);

  __syncthreads();

  const f32x4 zero4 = {0.f, 0.f, 0.f, 0.f};
  const float qs = 0.17677669529663687f;
  f32x4 sc[32];
  #pragma unroll
  for (int nt = 0; nt < 32; nt++) {
    int kk = nt * 16 + cl;
    size_t koff = (size_t)(b * 512 + kk) * 1152 + hh * 96 + 32 + cg * 8;
    bf16x8 kh = *(const bf16x8*)(qkvh + koff);
    bf16x8 kl = *(const bf16x8*)(qkvl + koff);
    f32x4 a = mfma_bf16(qh, kh, zero4);
    a = mfma_bf16(qh, kl, a);
    a = mfma_bf16(ql, kh, a);
    sc[nt] = a;
  }

  const size_t bc = (size_t)(b * 96 + layer * 12 + hh);
  #pragma unroll
  for (int nt = 0; nt < 32; nt++) {
    int kk = nt * 16 + cl;
    int mk = maskp[b * 512 + kk];
    #pragma unroll
    for (int i2 = 0; i2 < 4; i2++) {
      int qq = q0 + wid * 16 + cg * 4 + i2;
      float bias = bmat[(bc * 512 + qq) * 512 + kk];
      float vv = sc[nt][i2] * qs + bias;
      sc[nt][i2] = (mk == 0) ? -1e9f : vv;
    }
  }

  float inv[4];
  #pragma unroll
  for (int i2 = 0; i2 < 4; i2++) {
    float mx = -3e38f;
    #pragma unroll
    for (int nt = 0; nt < 32; nt++) mx = fmaxf(mx, sc[nt][i2]);
    mx = fmaxf(mx, __shfl_xor(mx, 1));
    mx = fmaxf(mx, __shfl_xor(mx, 2));
    mx = fmaxf(mx, __shfl_xor(mx, 4));
    mx = fmaxf(mx, __shfl_xor(mx, 8));
    float ss = 0.f;
    #pragma unroll
    for (int nt = 0; nt < 32; nt++) {
      float p = __expf(sc[nt][i2] - mx);
      sc[nt][i2] = p;
      ss += p;
    }
    ss += __shfl_xor(ss, 1);
    ss += __shfl_xor(ss, 2);
    ss += __shfl_xor(ss, 4);
    ss += __shfl_xor(ss, 8);
    inv[i2] = 1.f / ss;
  }

  f32x4 yacc[2] = {};
  for (int ks = 0; ks < 16; ks++) {
    #pragma unroll
    for (int half = 0; half < 2; half++) {
      int nt = ks * 2 + half;
      #pragma unroll
      for (int i2 = 0; i2 < 4; i2++) {
        u16 h2, l2; split2(sc[nt][i2] * inv[i2], h2, l2);
        pst_h[wid][cg * 4 + i2][half * 16 + cl] = h2;
        pst_l[wid][cg * 4 + i2][half * 16 + cl] = l2;
      }
    }
    __syncthreads();
    bf16x8 ph = *(const bf16x8*)&pst_h[wid][cl][cg * 8];
    bf16x8 pl = *(const bf16x8*)&pst_l[wid][cl][cg * 8];
    #pragma unroll
    for (int nt2 = 0; nt2 < 2; nt2++) {
      bf16x8 vh = *(const bf16x8*)&vT_h[nt2 * 16 + cl][ks * 32 + cg * 8];
      bf16x8 vl = *(const bf16x8*)&vT_l[nt2 * 16 + cl][ks * 32 + cg * 8];
      yacc[nt2] = mfma_bf16(ph, vh, yacc[nt2]);
      yacc[nt2] = mfma_bf16(ph, vl, yacc[nt2]);
      yacc[nt2] = mfma_bf16(pl, vh, yacc[nt2]);
    }
    __syncthreads();
  }

  #pragma unroll
  for (int nt2 = 0; nt2 < 2; nt2++) {
    #pragma unroll
    for (int i2 = 0; i2 < 4; i2++) {
      int qq = q0 + wid * 16 + cg * 4 + i2;
      int c = nt2 * 16 + cl;
      size_t oi = (size_t)(b * 512 + qq) * 384 + hh * 32 + c;
      ybuf[oi] = yacc[nt2][i2] * gate[oi];
    }
  }
}

// ---------------- wave-per-row small projection: O[row][n] = (relu?)A[row] . W[n] ----------------
template <int NOUT, int K, int RELU>
__global__ __launch_bounds__(256) void proj_kernel(
    const float* __restrict__ A, const float* __restrict__ W,
    const float* __restrict__ bias, float* __restrict__ O) {
  const int wid = threadIdx.x >> 6, lane = threadIdx.x & 63;
  const int row = blockIdx.x * 4 + wid;
  const float* a = A + (size_t)row * K;
  float av[K / 64];
  #pragma unroll
  for (int j = 0; j < K / 64; j++) {
    float v = a[lane + 64 * j];
    av[j] = RELU ? fmaxf(v, 0.f) : v;
  }
  float res = 0.f;
  #pragma unroll
  for (int n = 0; n < NOUT; n++) {
    float s = 0.f;
    #pragma unroll
    for (int j = 0; j < K / 64; j++) s += av[j] * W[n * K + lane + 64 * j];
    #pragma unroll
    for (int off = 32; off >= 1; off >>= 1) s += __shfl_xor(s, off);
    if (lane == n) res = s + bias[n];
  }
  if (lane < NOUT) O[(size_t)row * NOUT + lane] = res;
}

__device__ __forceinline__ void m3m(float* o, const float* a, const float* b) {
  #pragma unroll
  for (int i = 0; i < 3; i++)
    #pragma unroll
    for (int j = 0; j < 3; j++)
      o[i * 3 + j] = a[i * 3 + 0] * b[0 * 3 + j] + a[i * 3 + 1] * b[1 * 3 + j] + a[i * 3 + 2] * b[2 * 3 + j];
}
__device__ __forceinline__ void m3v(float* o, const float* a, const float* v) {
  #pragma unroll
  for (int i = 0; i < 3; i++)
    o[i] = a[i * 3 + 0] * v[0] + a[i * 3 + 1] * v[1] + a[i * 3 + 2] * v[2];
}

// ---------------- tail: angles norm + make_rigid + frames + atoms (scalar only) ----------------
__global__ __launch_bounds__(256) void tail_kernel(
    const float* __restrict__ angraw, const float* __restrict__ bbbuf,
    const int* __restrict__ aatype, const float* __restrict__ deff,
    const int* __restrict__ gidx, const float* __restrict__ amask,
    const float* __restrict__ lit,
    float* __restrict__ o_ang, float* __restrict__ o_un,
    float* __restrict__ o_bb4, float* __restrict__ o_rg4, float* __restrict__ o_pred) {
  int idx = blockIdx.x * 256 + threadIdx.x;
  if (idx >= 1024) return;
  float ang[14];
  #pragma unroll
  for (int a = 0; a < 7; a++) {
    float s0 = angraw[idx * 14 + a * 2], s1 = angraw[idx * 14 + a * 2 + 1];
    o_un[(idx * 7 + a) * 2] = s0; o_un[(idx * 7 + a) * 2 + 1] = s1;
    float d = sqrtf(fmaxf(s0 * s0 + s1 * s1, 1e-8f));
    ang[a * 2] = s0 / d; ang[a * 2 + 1] = s1 / d;
    o_ang[(idx * 7 + a) * 2] = ang[a * 2]; o_ang[(idx * 7 + a) * 2 + 1] = ang[a * 2 + 1];
  }
  const float* p = bbbuf + (size_t)idx * 9;
  float nx = p[0] - p[3], ny = p[1] - p[4], nz = p[2] - p[5];
  float cx = p[6] - p[3], cy = p[7] - p[4], cz = p[8] - p[5];
  const float eps = 1e-7f;
  float nrm = sqrtf(eps + cx * cx + cy * cy);
  float s1 = -cy / nrm, c1 = cx / nrm;
  float nrm2 = sqrtf(eps + cx * cx + cy * cy + cz * cz);
  float s2 = cz / nrm2, c2 = sqrtf(cx * cx + cy * cy) / nrm2;
  float Rc[9] = { c2 * c1, -c2 * s1, s2,
                  s1,      c1,       0.f,
                  -s2 * c1, s2 * s1, c2 };
  float n2y = Rc[3] * nx + Rc[4] * ny + Rc[5] * nz;
  float n2z = Rc[6] * nx + Rc[7] * ny + Rc[8] * nz;
  float nrm3 = sqrtf(eps + n2y * n2y + n2z * n2z);
  float sn = -n2z / nrm3, cn = n2y / nrm3;
  float Rm[9];
  Rm[0] = Rc[0]; Rm[1] = Rc[1]; Rm[2] = Rc[2];
  Rm[3] = cn * Rc[3] - sn * Rc[6];
  Rm[4] = cn * Rc[4] - sn * Rc[7];
  Rm[5] = cn * Rc[5] - sn * Rc[8];
  Rm[6] = sn * Rc[3] + cn * Rc[6];
  Rm[7] = sn * Rc[4] + cn * Rc[7];
  Rm[8] = sn * Rc[5] + cn * Rc[8];
  float Rb[9] = { Rm[0], Rm[3], Rm[6],
                  Rm[1], Rm[4], Rm[7],
                  Rm[2], Rm[5], Rm[8] };
  float tb[3] = { p[3] * 10.f, p[4] * 10.f, p[5] * 10.f };
  {
    float* o = o_bb4 + (size_t)idx * 16;
    o[0] = Rb[0]; o[1] = Rb[1]; o[2] = Rb[2]; o[3] = tb[0];
    o[4] = Rb[3]; o[5] = Rb[4]; o[6] = Rb[5]; o[7] = tb[1];
    o[8] = Rb[6]; o[9] = Rb[7]; o[10] = Rb[8]; o[11] = tb[2];
    o[12] = 0.f; o[13] = 0.f; o[14] = 0.f; o[15] = 1.f;
  }
  int aa = aatype[idx];
  float Rf[8][9], tf[8][3];
  for (int g = 0; g < 8; g++) {
    const float* d4 = deff + ((size_t)aa * 8 + g) * 16;
    float sa = 0.f, ca = 1.f;
    if (g > 0) { sa = ang[(g - 1) * 2]; ca = ang[(g - 1) * 2 + 1]; }
    #pragma unroll
    for (int i = 0; i < 3; i++) {
      float d0 = d4[i * 4 + 0], d1 = d4[i * 4 + 1], d2 = d4[i * 4 + 2];
      Rf[g][i * 3 + 0] = d0;
      Rf[g][i * 3 + 1] = d1 * ca + d2 * sa;
      Rf[g][i * 3 + 2] = -d1 * sa + d2 * ca;
      tf[g][i] = d4[i * 4 + 3];
    }
  }
  float Rall[8][9], tall[8][3];
  for (int g = 0; g < 5; g++) {
    #pragma unroll
    for (int i = 0; i < 9; i++) Rall[g][i] = Rf[g][i];
    #pragma unroll
    for (int i = 0; i < 3; i++) tall[g][i] = tf[g][i];
  }
  m3m(Rall[5], Rf[4], Rf[5]); m3v(tall[5], Rf[4], tf[5]);
  tall[5][0] += tf[4][0]; tall[5][1] += tf[4][1]; tall[5][2] += tf[4][2];
  m3m(Rall[6], Rall[5], Rf[6]); m3v(tall[6], Rall[5], tf[6]);
  tall[6][0] += tall[5][0]; tall[6][1] += tall[5][1]; tall[6][2] += tall[5][2];
  m3m(Rall[7], Rall[6], Rf[7]); m3v(tall[7], Rall[6], tf[7]);
  tall[7][0] += tall[6][0]; tall[7][1] += tall[6][1]; tall[7][2] += tall[6][2];
  float RG[8][9], TG[8][3];
  for (int g = 0; g < 8; g++) {
    m3m(RG[g], Rb, Rall[g]);
    m3v(TG[g], Rb, tall[g]);
    TG[g][0] += tb[0]; TG[g][1] += tb[1]; TG[g][2] += tb[2];
    float* o = o_rg4 + ((size_t)idx * 8 + g) * 16;
    o[0] = RG[g][0]; o[1] = RG[g][1]; o[2] = RG[g][2]; o[3] = TG[g][0];
    o[4] = RG[g][3]; o[5] = RG[g][4]; o[6] = RG[g][5]; o[7] = TG[g][1];
    o[8] = RG[g][6]; o[9] = RG[g][7]; o[10] = RG[g][8]; o[11] = TG[g][2];
    o[12] = 0.f; o[13] = 0.f; o[14] = 0.f; o[15] = 1.f;
  }
  for (int a = 0; a < 14; a++) {
    int gi = gidx[aa * 14 + a];
    const float* lp = lit + ((size_t)aa * 14 + a) * 3;
    float mk = amask[aa * 14 + a];
    float px = RG[gi][0] * lp[0] + RG[gi][1] * lp[1] + RG[gi][2] * lp[2] + TG[gi][0];
    float py = RG[gi][3] * lp[0] + RG[gi][4] * lp[1] + RG[gi][5] * lp[2] + TG[gi][1];
    float pz = RG[gi][6] * lp[0] + RG[gi][7] * lp[1] + RG[gi][8] * lp[2] + TG[gi][2];
    float* op = o_pred + ((size_t)idx * 14 + a) * 3;
    op[0] = px * mk; op[1] = py * mk; op[2] = pz * mk;
  }
}

extern "C" void kernel_launch(void* const* d_in, const int* in_sizes, int n_in,
                              void* d_out, int out_size, void* d_ws, size_t ws_size,
                              hipStream_t stream) {
  (void)in_sizes; (void)n_in; (void)out_size; (void)ws_size;
  const float* s_in    = (const float*)d_in[0];
  const float* z_in    = (const float*)d_in[1];
  const int*   aatype  = (const int*)d_in[2];
  const int*   maskp   = (const int*)d_in[3];
  const float* ln_s_g  = (const float*)d_in[4];
  const float* ln_s_b  = (const float*)d_in[5];
  const float* ln_z_g  = (const float*)d_in[6];
  const float* ln_z_b  = (const float*)d_in[7];
  const float* w_in    = (const float*)d_in[8];
  const float* b_in    = (const float*)d_in[9];
  const float* w_b     = (const float*)d_in[10];
  const float* b_b     = (const float*)d_in[11];
  const float* attn_ln_g = (const float*)d_in[12];
  const float* attn_ln_b = (const float*)d_in[13];
  const float* attn_wqkv = (const float*)d_in[14];
  const float* attn_wo   = (const float*)d_in[15];
  const float* attn_bo   = (const float*)d_in[16];
  const float* attn_wg   = (const float*)d_in[17];
  const float* attn_bg   = (const float*)d_in[18];
  const float* tr_ln_g   = (const float*)d_in[19];
  const float* tr_ln_b   = (const float*)d_in[20];
  const float* tr_w1     = (const float*)d_in[21];
  const float* tr_b1     = (const float*)d_in[22];
  const float* tr_w2     = (const float*)d_in[23];
  const float* tr_b2     = (const float*)d_in[24];
  const float* w_bb      = (const float*)d_in[25];
  const float* b_bb      = (const float*)d_in[26];
  const float* ar_win    = (const float*)d_in[27];
  const float* ar_bin    = (const float*)d_in[28];
  const float* ar_winit  = (const float*)d_in[29];
  const float* ar_binit  = (const float*)d_in[30];
  const float* ar_w1     = (const float*)d_in[31];
  const float* ar_b1     = (const float*)d_in[32];
  const float* ar_w2     = (const float*)d_in[33];
  const float* ar_b2     = (const float*)d_in[34];
  const float* ar_wout   = (const float*)d_in[35];
  const float* ar_bout   = (const float*)d_in[36];
  const float* def_frames= (const float*)d_in[37];
  const int*   group_idx = (const int*)d_in[38];
  const float* atom_mask = (const float*)d_in[39];
  const float* lit_pos   = (const float*)d_in[40];

  char* p = (char*)d_ws;
  float* bmat   = (float*)p;          p += 201326592;
  float* s_init = (float*)p;          p += 1572864;
  float* s_cur  = (float*)p;          p += 1572864;
  u16*   qkvh   = (u16*)p;            p += 2359296;
  u16*   qkvl   = (u16*)p;            p += 2359296;
  float* gbuf   = (float*)p;          p += 1572864;
  float* ybuf   = (float*)p;          p += 1572864;
  float* h1buf  = (float*)p;          p += 1572864;
  float* abuf   = (float*)p;          p += 524288;
  float* htmp   = (float*)p;          p += 524288;
  float* pbuf   = (float*)p;          p += 65536;
  float* bbbuf  = (float*)p;          p += 36864;
  float* angraw = (float*)p;          p += 57344;
  u16* ps_qkvw  = (u16*)p;            p += 14155776;
  u16* ps_wg    = (u16*)p;            p += 4718592;
  u16* ps_wo    = (u16*)p;            p += 4718592;
  u16* ps_tr1   = (u16*)p;            p += 4718592;
  u16* ps_tr2   = (u16*)p;            p += 4718592;
  u16* ps_win   = (u16*)p;            p += 589824;
  u16* ps_wb    = (u16*)p;            p += 49152;
  u16* ps_arwin = (u16*)p;            p += 294912;
  u16* ps_arwinit = (u16*)p;          p += 294912;
  u16* ps_arw1  = (u16*)p;            p += 196608;
  u16* ps_arw2  = (u16*)p;            p += 196608;

  float* out    = (float*)d_out;
  float* o_ang  = out;
  float* o_un   = out + 14336;
  float* o_bb4  = out + 28672;
  float* o_rg4  = out + 45056;
  float* o_pred = out + 176128;
  float* o_s    = out + 219136;

  // --- weight pre-split ---
  Prep2Args p2;
  p2.j[0] = {attn_wqkv, ps_qkvw, 3538944};
  p2.j[1] = {attn_wg,   ps_wg,   1179648};
  p2.j[2] = {attn_wo,   ps_wo,   1179648};
  p2.j[3] = {tr_w1,     ps_tr1,  1179648};
  p2.j[4] = {tr_w2,     ps_tr2,  1179648};
  p2.j[5] = {w_in,      ps_win,  147456};
  p2.j[6] = {w_b,       ps_wb,   12288};
  prep2_kernel<<<2048, 256, 0, stream>>>(p2, 2104320);
  Prep3Args p3;
  p3.j[0] = {ar_win,   ps_arwin,   49152};
  p3.j[1] = {ar_winit, ps_arwinit, 49152};
  p3.j[2] = {ar_w1,    ps_arw1,    32768};
  p3.j[3] = {ar_w2,    ps_arw2,    32768};
  prep3_kernel<<<160, 256, 0, stream>>>(p3, 40960);

  // s_init = LN(s)
  ln_kernel<<<256, 256, 0, stream>>>(s_in, ln_s_g, ln_s_b, s_init, 1024, 384);
  // s_cur = s_init @ w_in^T + b_in (+stats)
  gemm_kernel<2, 0, 0, 0, 0, 1, 0><<<dim3(6, 32), 128, 0, stream>>>(
      s_init, nullptr, nullptr, nullptr, ps_win, ps_win + 147456, nullptr,
      b_in, s_cur, nullptr, pbuf, 1024, 384, 384);
  // bmat
  zbmat_kernel<<<1024, 512, 0, stream>>>(z_in, ln_z_g, ln_z_b, ps_wb, ps_wb + 12288, b_b, bmat);

  for (int l = 0; l < 8; ++l) {
    gemm_qkvg_kernel<<<dim3(24, 32), 128, 0, stream>>>(
        s_cur, pbuf, attn_ln_g + l * 384, attn_ln_b + l * 384,
        ps_qkvw + (size_t)l * 442368, ps_qkvw + 3538944 + (size_t)l * 442368,
        ps_wg + (size_t)l * 147456, ps_wg + 1179648 + (size_t)l * 147456,
        attn_bg + l * 384, qkvh, qkvl, gbuf);
    attn_kernel<<<384, 128, 0, stream>>>(qkvh, qkvl, bmat, maskp, gbuf, ybuf, l);
    gemm_kernel<2, 0, 0, 0, 1, 1, 0><<<dim3(6, 32), 128, 0, stream>>>(
        ybuf, nullptr, nullptr, nullptr,
        ps_wo + (size_t)l * 147456, ps_wo + 1179648 + (size_t)l * 147456, nullptr,
        attn_bo + l * 384, s_cur, nullptr, pbuf, 1024, 384, 384);
    gemm_kernel<2, 1, 0, 1, 0, 0, 0><<<dim3(6, 32), 128, 0, stream>>>(
        s_cur, pbuf, tr_ln_g + l * 384, tr_ln_b + l * 384,
        ps_tr1 + (size_t)l * 147456, ps_tr1 + 1179648 + (size_t)l * 147456, nullptr,
        tr_b1 + l * 384, h1buf, nullptr, nullptr, 1024, 384, 384);
    if (l < 7)
      gemm_kernel<2, 0, 0, 0, 1, 1, 0><<<dim3(6, 32), 128, 0, stream>>>(
          h1buf, nullptr, nullptr, nullptr,
          ps_tr2 + (size_t)l * 147456, ps_tr2 + 1179648 + (size_t)l * 147456, nullptr,
          tr_b2 + l * 384, s_cur, nullptr, pbuf, 1024, 384, 384);
    else
      gemm_kernel<2, 0, 0, 0, 1, 1, 1><<<dim3(6, 32), 128, 0, stream>>>(
          h1buf, nullptr, nullptr, nullptr,
          ps_tr2 + (size_t)l * 147456, ps_tr2 + 1179648 + (size_t)l * 147456, nullptr,
          tr_b2 + l * 384, s_cur, o_s, pbuf, 1024, 384, 384);
  }

  // angle resnet (3-split, pre-split W)
  gemm_kernel<3, 0, 1, 0, 0, 0, 0><<<dim3(2, 32), 128, 0, stream>>>(
      s_cur, nullptr, nullptr, nullptr,
      ps_arwin, ps_arwin + 49152, ps_arwin + 98304,
      ar_bin, abuf, nullptr, nullptr, 1024, 128, 384);
  gemm_kernel<3, 0, 1, 0, 1, 0, 0><<<dim3(2, 32), 128, 0, stream>>>(
      s_init, nullptr, nullptr, nullptr,
      ps_arwinit, ps_arwinit + 49152, ps_arwinit + 98304,
      ar_binit, abuf, nullptr, nullptr, 1024, 128, 384);
  for (int j = 0; j < 2; ++j) {
    gemm_kernel<3, 0, 1, 0, 0, 0, 0><<<dim3(2, 32), 128, 0, stream>>>(
        abuf, nullptr, nullptr, nullptr,
        ps_arw1 + j * 16384, ps_arw1 + 32768 + j * 16384, ps_arw1 + 65536 + j * 16384,
        ar_b1 + j * 128, htmp, nullptr, nullptr, 1024, 128, 128);
    gemm_kernel<3, 0, 1, 0, 1, 0, 0><<<dim3(2, 32), 128, 0, stream>>>(
        htmp, nullptr, nullptr, nullptr,
        ps_arw2 + j * 16384, ps_arw2 + 32768 + j * 16384, ps_arw2 + 65536 + j * 16384,
        ar_b2 + j * 128, abuf, nullptr, nullptr, 1024, 128, 128);
  }

  // projections + tail
  proj_kernel<9, 384, 0><<<256, 256, 0, stream>>>(s_cur, w_bb, b_bb, bbbuf);
  proj_kernel<14, 128, 1><<<256, 256, 0, stream>>>(abuf, ar_wout, ar_bout, angraw);
  tail_kernel<<<4, 256, 0, stream>>>(angraw, bbbuf, aatype, def_frames, group_idx,
                                     atom_mask, lit_pos, o_ang, o_un, o_bb4, o_rg4, o_pred);
}